// Round 5
// baseline (2331.350 us; speedup 1.0000x reference)
//
#include <hip/hip_runtime.h>

#define T_STEPS 336
#define NWG 32

// Device-global scratch (no d_ws dependence). Every element is written each
// call before any read of it (no cross-call state; replay-safe).
__device__ float g_xg[336 * 2048];    // input-gate projection for batch 255
__device__ float g_h[337 * 512];      // h_0 .. h_336 (slot 0 zeroed by prep)
__device__ float g_blw[256 * 512];    // sampled BayesianLinear weight
__device__ float g_blb[256];          // sampled BayesianLinear bias
__device__ float g_whh[512 * 2048];   // sampled Whh
__device__ int   g_flag[NWG];         // flag[r] = t+1  <=>  WG r published h_{t+1}

__device__ __forceinline__ float softplus_f(float x) {
  return (x > 20.f) ? x : log1pf(__expf(x));
}
__device__ __forceinline__ float sigmoid_f(float x) {
  return 1.f / (1.f + __expf(-x));
}

// ---------------- prep ----------------
// blocks    0..2687 : g_xg[t][g] = (x[255,t]*drop_x[255,t]) @ Wih + b  (sampled)
// blocks 2688..3199 : sample BLW -> g_blw
// block  3200       : sample BLb -> g_blb; zero g_h[0][:]; zero g_flag[:]
// blocks 3201..7296 : sample Whh -> g_whh
__global__ __launch_bounds__(256) void prep_kernel(
    const float* __restrict__ x, const float* __restrict__ drop_x,
    const float* __restrict__ wih_mu, const float* __restrict__ wih_rho, const float* __restrict__ eps_wih,
    const float* __restrict__ whh_mu, const float* __restrict__ whh_rho, const float* __restrict__ eps_whh,
    const float* __restrict__ b_mu, const float* __restrict__ b_rho, const float* __restrict__ eps_b,
    const float* __restrict__ blw_mu, const float* __restrict__ blw_rho, const float* __restrict__ eps_blw,
    const float* __restrict__ blb_mu, const float* __restrict__ blb_rho, const float* __restrict__ eps_blb)
{
  const int bid = blockIdx.x, tid = threadIdx.x;
  if (bid < 2688) {
    const int gid = bid * 256 + tid;
    const int t = gid >> 11;        // 0..335
    const int g = gid & 2047;       // gate column
    float acc = b_mu[g] + softplus_f(b_rho[g]) * eps_b[g];
    const int xoff = (255 * 336 + t) * 16;   // only batch 255 survives the reshape quirk
    #pragma unroll
    for (int i = 0; i < 16; ++i) {
      float xv = x[xoff + i] * drop_x[xoff + i];
      int wi = i * 2048 + g;
      float w = wih_mu[wi] + softplus_f(wih_rho[wi]) * eps_wih[wi];
      acc = fmaf(xv, w, acc);
    }
    g_xg[gid] = acc;
  } else if (bid < 3200) {
    const int e = (bid - 2688) * 256 + tid;   // < 131072
    g_blw[e] = blw_mu[e] + softplus_f(blw_rho[e]) * eps_blw[e];
  } else if (bid == 3200) {
    g_blb[tid] = blb_mu[tid] + softplus_f(blb_rho[tid]) * eps_blb[tid];
    g_h[tid] = 0.f; g_h[256 + tid] = 0.f;     // h_0 = 0
    if (tid < NWG) g_flag[tid] = 0;
  } else {
    const int e = (bid - 3201) * 256 + tid;   // < 1048576
    g_whh[e] = whh_mu[e] + softplus_f(whh_rho[e]) * eps_whh[e];
  }
}

// ---------------- persistent LSTM recurrence ----------------
// 32 WGs x 512 threads, launched ONCE. WG r owns h-indices [16r, 16r+16).
// Thread (seg=tid>>6, cl=tid&63): column col = gate*512 + 16r + kl over
// row range [64*seg, 64*seg+64); 64 sampled weights live in registers.
// Per step: spin on flags (agent acquire) -> load h (agent) -> dot ->
// LDS partial reduce -> wave-0 shfl gate exchange -> nonlinearity ->
// publish 16 h (agent) -> release-store own flag.
__global__ __launch_bounds__(512) void lstm_kernel() {
  const int r = blockIdx.x;         // 0..31
  const int tid = threadIdx.x;      // 0..511
  const int cl = tid & 63;
  const int seg = tid >> 6;         // 0..7
  const int gate = cl >> 4, kl = cl & 15;
  const int col = gate * 512 + r * 16 + kl;
  const int row0 = seg * 64;

  // One-time: my 64 sampled weights into registers.
  float w[64];
  #pragma unroll 16
  for (int j = 0; j < 64; ++j) w[j] = g_whh[(row0 + j) * 2048 + col];

  __shared__ float hs[512];
  __shared__ float part[8][64];

  float c = 0.f;                    // cell state (valid on wave-0 lanes 0..15)

  for (int t = 0; t < T_STEPS; ++t) {
    // Prefetch xg for this step (independent of h -> overlaps the spin).
    float xgv = 0.f;
    if (tid < 64) xgv = g_xg[t * 2048 + gate * 512 + r * 16 + kl];

    // Wait until every WG has published h_t (t=0 passes immediately).
    if (tid < NWG) {
      while (__hip_atomic_load(&g_flag[tid], __ATOMIC_ACQUIRE,
                               __HIP_MEMORY_SCOPE_AGENT) < t) { }
    }
    __syncthreads();

    // Load h_t (agent scope: bypass stale per-XCD L2).
    hs[tid] = __hip_atomic_load(&g_h[t * 512 + tid], __ATOMIC_RELAXED,
                                __HIP_MEMORY_SCOPE_AGENT);
    __syncthreads();

    // Partial dot over my 64 rows (4 accumulators to shorten dep chain).
    float a0 = 0.f, a1 = 0.f, a2 = 0.f, a3 = 0.f;
    #pragma unroll
    for (int j = 0; j < 64; j += 4) {
      a0 = fmaf(hs[row0 + j],     w[j],     a0);
      a1 = fmaf(hs[row0 + j + 1], w[j + 1], a1);
      a2 = fmaf(hs[row0 + j + 2], w[j + 2], a2);
      a3 = fmaf(hs[row0 + j + 3], w[j + 3], a3);
    }
    part[seg][cl] = (a0 + a1) + (a2 + a3);
    __syncthreads();

    // Wave 0 finishes: reduce 8 segments, exchange gates via shfl, nonlin.
    if (tid < 64) {
      float g = xgv + ((part[0][tid] + part[1][tid]) + (part[2][tid] + part[3][tid]))
                    + ((part[4][tid] + part[5][tid]) + (part[6][tid] + part[7][tid]));
      float vi = __shfl(g, kl);           // gate 0 (i) value for index kl
      float vf = __shfl(g, kl + 16);      // gate 1 (f)
      float vg = __shfl(g, kl + 32);      // gate 2 (g)
      float vo = __shfl(g, kl + 48);      // gate 3 (o)
      if (tid < 16) {
        float ig = sigmoid_f(vi);
        float fg = sigmoid_f(vf);
        float gg = tanhf(vg);
        float og = sigmoid_f(vo);
        c = fg * c + ig * gg;
        float h = og * tanhf(c);
        __hip_atomic_store(&g_h[(t + 1) * 512 + r * 16 + tid], h,
                           __ATOMIC_RELAXED, __HIP_MEMORY_SCOPE_AGENT);
      }
    }
    // Release: wave-wide vmcnt drain orders lanes 0..15's h stores (same wave)
    // before the flag store becomes visible.
    if (tid == 0) {
      __hip_atomic_store(&g_flag[r], t + 1, __ATOMIC_RELEASE,
                         __HIP_MEMORY_SCOPE_AGENT);
    }
    // No extra barrier needed: waves 1..7 only touch hs/part again after the
    // next iteration's __syncthreads, which wave 0 reaches after publishing.
  }
}

// ---------------- head ----------------
// block j: last[j] = g_h[81+j]  (reshape(T,B,H)[-1] => h_{t=80+j} of batch 255)
// y[l] = relu(last*drop_h[j] . BLW[l] + BLb[l]) * drop_l[j,l]
// out[j,o] = sum_l y[l]*lin_w[o,l]
__global__ __launch_bounds__(256) void head_kernel(
    const float* __restrict__ drop_h, const float* __restrict__ drop_l,
    const float* __restrict__ lin_w, float* __restrict__ out)
{
  const int j = blockIdx.x, tid = threadIdx.x;
  __shared__ float hd[512];
  __shared__ float y[256];

  for (int k = tid; k < 512; k += 256)
    hd[k] = g_h[(81 + j) * 512 + k] * drop_h[j * 512 + k];
  __syncthreads();

  {
    const int l = tid;
    float acc = g_blb[l];
    const float* wrow = g_blw + l * 512;
    #pragma unroll 8
    for (int k = 0; k < 512; ++k) acc = fmaf(hd[k], wrow[k], acc);
    acc = fmaxf(acc, 0.f);
    y[l] = acc * drop_l[j * 256 + l];
  }
  __syncthreads();

  if (tid < 10) {
    float acc = 0.f;
    const float* lrow = lin_w + tid * 256;
    #pragma unroll 8
    for (int l = 0; l < 256; ++l) acc = fmaf(y[l], lrow[l], acc);
    out[j * 10 + tid] = acc;
  }
}

// ---------------- launch ----------------
extern "C" void kernel_launch(void* const* d_in, const int* in_sizes, int n_in,
                              void* d_out, int out_size, void* d_ws, size_t ws_size,
                              hipStream_t stream) {
  const float* x        = (const float*)d_in[0];
  const float* drop_x   = (const float*)d_in[1];
  const float* drop_h   = (const float*)d_in[2];
  const float* drop_l   = (const float*)d_in[3];
  const float* wih_mu   = (const float*)d_in[4];
  const float* wih_rho  = (const float*)d_in[5];
  const float* eps_wih  = (const float*)d_in[6];
  const float* whh_mu   = (const float*)d_in[7];
  const float* whh_rho  = (const float*)d_in[8];
  const float* eps_whh  = (const float*)d_in[9];
  const float* b_mu     = (const float*)d_in[10];
  const float* b_rho    = (const float*)d_in[11];
  const float* eps_b    = (const float*)d_in[12];
  const float* blw_mu   = (const float*)d_in[13];
  const float* blw_rho  = (const float*)d_in[14];
  const float* eps_blw  = (const float*)d_in[15];
  const float* blb_mu   = (const float*)d_in[16];
  const float* blb_rho  = (const float*)d_in[17];
  const float* eps_blb  = (const float*)d_in[18];
  const float* lin_w    = (const float*)d_in[19];

  prep_kernel<<<7297, 256, 0, stream>>>(
      x, drop_x, wih_mu, wih_rho, eps_wih, whh_mu, whh_rho, eps_whh,
      b_mu, b_rho, eps_b, blw_mu, blw_rho, eps_blw, blb_mu, blb_rho, eps_blb);

  lstm_kernel<<<NWG, 512, 0, stream>>>();

  head_kernel<<<256, 256, 0, stream>>>(drop_h, drop_l, lin_w, (float*)d_out);
}

// Round 6
// 791.899 us; speedup vs baseline: 2.9440x; 2.9440x over previous
//
#include <hip/hip_runtime.h>

#define T_STEPS 336
#define NWG 32

typedef unsigned long long u64;

// Device-global scratch. Every element is re-written each call before any
// read of it (prep re-inits g_hh/g_blb/g_blw/g_xg; lstm writes g_h).
__device__ float g_xg[336 * 2048];    // input-gate projection for batch 255
__device__ float g_h[337 * 512];      // h_1 .. h_336 (head reads t>=81 only)
__device__ float g_blw[256 * 512];    // sampled BayesianLinear weight
__device__ float g_blb[256];          // sampled BayesianLinear bias
__device__ u64   g_hh[2][512];        // parity-double-buffered (tag<<32 | h bits)

__device__ __forceinline__ float softplus_f(float x) {
  return (x > 20.f) ? x : log1pf(__expf(x));
}
__device__ __forceinline__ float sigmoid_f(float x) {
  return 1.f / (1.f + __expf(-x));
}
// Clamped fast tanh: exact to ~1e-7 in the pre-clamp range; tanh saturates
// to +-1 well before |x|=15, and the clamp prevents __expf overflow->NaN.
__device__ __forceinline__ float tanh_f(float x) {
  x = fminf(fmaxf(x, -15.f), 15.f);
  float e = __expf(-2.f * x);
  return (1.f - e) / (1.f + e);
}

// ---------------- prep ----------------
// blocks    0..2687 : g_xg[t][g] = (x[255,t]*drop_x[255,t]) @ Wih + b  (sampled)
// blocks 2688..3199 : sample BLW -> g_blw
// block  3200       : sample BLb -> g_blb; init g_hh (tag0 = h_0 = 0)
__global__ __launch_bounds__(256) void prep_kernel(
    const float* __restrict__ x, const float* __restrict__ drop_x,
    const float* __restrict__ wih_mu, const float* __restrict__ wih_rho, const float* __restrict__ eps_wih,
    const float* __restrict__ b_mu, const float* __restrict__ b_rho, const float* __restrict__ eps_b,
    const float* __restrict__ blw_mu, const float* __restrict__ blw_rho, const float* __restrict__ eps_blw,
    const float* __restrict__ blb_mu, const float* __restrict__ blb_rho, const float* __restrict__ eps_blb)
{
  const int bid = blockIdx.x, tid = threadIdx.x;
  if (bid < 2688) {
    const int gid = bid * 256 + tid;
    const int t = gid >> 11;        // 0..335
    const int g = gid & 2047;       // gate column
    float acc = b_mu[g] + softplus_f(b_rho[g]) * eps_b[g];
    const int xoff = (255 * 336 + t) * 16;   // only batch 255 survives the reshape quirk
    #pragma unroll
    for (int i = 0; i < 16; ++i) {
      float xv = x[xoff + i] * drop_x[xoff + i];
      int wi = i * 2048 + g;
      float w = wih_mu[wi] + softplus_f(wih_rho[wi]) * eps_wih[wi];
      acc = fmaf(xv, w, acc);
    }
    g_xg[gid] = acc;
  } else if (bid < 3200) {
    const int e = (bid - 2688) * 256 + tid;   // < 131072
    g_blw[e] = blw_mu[e] + softplus_f(blw_rho[e]) * eps_blw[e];
  } else {
    g_blb[tid] = blb_mu[tid] + softplus_f(blb_rho[tid]) * eps_blb[tid];
    // h_0 = 0 with tag 0 in buf[0]; buf[1] zeroed (tag 0 != 1 -> no false pass).
    // Relaxed agent stores: land at the coherence point the lstm polls.
    __hip_atomic_store(&g_hh[0][tid],       0ULL, __ATOMIC_RELAXED, __HIP_MEMORY_SCOPE_AGENT);
    __hip_atomic_store(&g_hh[0][256 + tid], 0ULL, __ATOMIC_RELAXED, __HIP_MEMORY_SCOPE_AGENT);
    __hip_atomic_store(&g_hh[1][tid],       0ULL, __ATOMIC_RELAXED, __HIP_MEMORY_SCOPE_AGENT);
    __hip_atomic_store(&g_hh[1][256 + tid], 0ULL, __ATOMIC_RELAXED, __HIP_MEMORY_SCOPE_AGENT);
  }
}

// ---------------- persistent LSTM recurrence ----------------
// 32 WGs x 512 threads, launched ONCE. WG r owns h-indices [16r, 16r+16).
// Thread (seg=tid>>6, cl=tid&63): column col = gate*512 + 16r + kl over rows
// [64*seg, 64*seg+64); samples its own 64 Whh weights into REGISTERS (full
// unroll -> no scratch demotion; round-5's `#pragma unroll 16` left w[] in
// scratch, VGPR_Count=32 proved it).
// Sync: tag==t poll on own g_hh slot, ALL relaxed agent atomics -> no
// buffer_inv/buffer_wbl2 cache-maintenance in the loop (round-5 killer).
__global__ __launch_bounds__(512) void lstm_kernel(
    const float* __restrict__ whh_mu, const float* __restrict__ whh_rho,
    const float* __restrict__ eps_whh)
{
  const int r = blockIdx.x;         // 0..31
  const int tid = threadIdx.x;      // 0..511
  const int cl = tid & 63;
  const int seg = tid >> 6;         // 0..7
  const int gate = cl >> 4, kl = cl & 15;
  const int col = gate * 512 + r * 16 + kl;
  const int row0 = seg * 64;

  // One-time: sample my 64 weights straight into registers.
  float w[64];
  #pragma unroll
  for (int j = 0; j < 64; ++j) {
    const int idx = (row0 + j) * 2048 + col;
    w[j] = whh_mu[idx] + softplus_f(whh_rho[idx]) * eps_whh[idx];
  }

  __shared__ float hs[512];
  __shared__ float part[8][64];

  float c = 0.f;                    // cell state (valid on wave-0 lanes 0..15)

  for (int t = 0; t < T_STEPS; ++t) {
    // Prefetch xg for this step (independent of h; overlaps the poll).
    float xgv = 0.f;
    if (tid < 64) xgv = g_xg[t * 2048 + col];

    // Poll my slot until its tag == t; the h value rides along with the tag.
    const u64* slot = &g_hh[t & 1][tid];
    u64 v;
    do {
      v = __hip_atomic_load(slot, __ATOMIC_RELAXED, __HIP_MEMORY_SCOPE_AGENT);
    } while ((unsigned)(v >> 32) != (unsigned)t);
    hs[tid] = __uint_as_float((unsigned)v);
    __syncthreads();

    // Partial dot over my 64 rows (4 accumulators shorten the dep chain).
    float a0 = 0.f, a1 = 0.f, a2 = 0.f, a3 = 0.f;
    #pragma unroll
    for (int j = 0; j < 64; j += 4) {
      a0 = fmaf(hs[row0 + j],     w[j],     a0);
      a1 = fmaf(hs[row0 + j + 1], w[j + 1], a1);
      a2 = fmaf(hs[row0 + j + 2], w[j + 2], a2);
      a3 = fmaf(hs[row0 + j + 3], w[j + 3], a3);
    }
    part[seg][cl] = (a0 + a1) + (a2 + a3);
    __syncthreads();

    // Wave 0: reduce 8 segments, exchange gates via shfl, nonlinearity, publish.
    if (tid < 64) {
      float g = xgv + ((part[0][tid] + part[1][tid]) + (part[2][tid] + part[3][tid]))
                    + ((part[4][tid] + part[5][tid]) + (part[6][tid] + part[7][tid]));
      float vi = __shfl(g, kl);           // gate i value for h-index kl
      float vf = __shfl(g, kl + 16);      // gate f
      float vg = __shfl(g, kl + 32);      // gate g
      float vo = __shfl(g, kl + 48);      // gate o
      if (tid < 16) {
        float ig = sigmoid_f(vi);
        float fg = sigmoid_f(vf);
        float gg = tanh_f(vg);
        float og = sigmoid_f(vo);
        c = fg * c + ig * gg;
        float h = og * tanh_f(c);
        g_h[(t + 1) * 512 + r * 16 + tid] = h;   // for head (kernel-end flush)
        u64 pv = (((u64)(unsigned)(t + 1)) << 32) | (u64)__float_as_uint(h);
        __hip_atomic_store(&g_hh[(t + 1) & 1][r * 16 + tid], pv,
                           __ATOMIC_RELAXED, __HIP_MEMORY_SCOPE_AGENT);
      }
    }
    // No trailing barrier: hs rewrite is gated by the next poll (which needs
    // our publish), part rewrite by the next iteration's first barrier.
  }
}

// ---------------- head ----------------
// block j: last[j] = g_h[81+j]  (reshape(T,B,H)[-1] => h_{t=80+j} of batch 255)
// y[l] = relu(last*drop_h[j] . BLW[l] + BLb[l]) * drop_l[j,l]
// out[j,o] = sum_l y[l]*lin_w[o,l]
__global__ __launch_bounds__(256) void head_kernel(
    const float* __restrict__ drop_h, const float* __restrict__ drop_l,
    const float* __restrict__ lin_w, float* __restrict__ out)
{
  const int j = blockIdx.x, tid = threadIdx.x;
  __shared__ float hd[512];
  __shared__ float y[256];

  for (int k = tid; k < 512; k += 256)
    hd[k] = g_h[(81 + j) * 512 + k] * drop_h[j * 512 + k];
  __syncthreads();

  {
    const int l = tid;
    float acc = g_blb[l];
    const float* wrow = g_blw + l * 512;
    #pragma unroll 8
    for (int k = 0; k < 512; ++k) acc = fmaf(hd[k], wrow[k], acc);
    acc = fmaxf(acc, 0.f);
    y[l] = acc * drop_l[j * 256 + l];
  }
  __syncthreads();

  if (tid < 10) {
    float acc = 0.f;
    const float* lrow = lin_w + tid * 256;
    #pragma unroll 8
    for (int l = 0; l < 256; ++l) acc = fmaf(y[l], lrow[l], acc);
    out[j * 10 + tid] = acc;
  }
}

// ---------------- launch ----------------
extern "C" void kernel_launch(void* const* d_in, const int* in_sizes, int n_in,
                              void* d_out, int out_size, void* d_ws, size_t ws_size,
                              hipStream_t stream) {
  const float* x        = (const float*)d_in[0];
  const float* drop_x   = (const float*)d_in[1];
  const float* drop_h   = (const float*)d_in[2];
  const float* drop_l   = (const float*)d_in[3];
  const float* wih_mu   = (const float*)d_in[4];
  const float* wih_rho  = (const float*)d_in[5];
  const float* eps_wih  = (const float*)d_in[6];
  const float* whh_mu   = (const float*)d_in[7];
  const float* whh_rho  = (const float*)d_in[8];
  const float* eps_whh  = (const float*)d_in[9];
  const float* b_mu     = (const float*)d_in[10];
  const float* b_rho    = (const float*)d_in[11];
  const float* eps_b    = (const float*)d_in[12];
  const float* blw_mu   = (const float*)d_in[13];
  const float* blw_rho  = (const float*)d_in[14];
  const float* eps_blw  = (const float*)d_in[15];
  const float* blb_mu   = (const float*)d_in[16];
  const float* blb_rho  = (const float*)d_in[17];
  const float* eps_blb  = (const float*)d_in[18];
  const float* lin_w    = (const float*)d_in[19];

  prep_kernel<<<3201, 256, 0, stream>>>(
      x, drop_x, wih_mu, wih_rho, eps_wih,
      b_mu, b_rho, eps_b, blw_mu, blw_rho, eps_blw, blb_mu, blb_rho, eps_blb);

  lstm_kernel<<<NWG, 512, 0, stream>>>(whh_mu, whh_rho, eps_whh);

  head_kernel<<<256, 256, 0, stream>>>(drop_h, drop_l, lin_w, (float*)d_out);
}

// Round 7
// 726.363 us; speedup vs baseline: 3.2096x; 1.0902x over previous
//
#include <hip/hip_runtime.h>

#define T_STEPS 336
#define NWG 32

typedef unsigned long long u64;

// Device-global scratch. g_hh tags are re-initialized by prep each call
// (device globals are NOT re-poisoned by the harness; stale tags from a
// previous run would satisfy polls -> must re-init every launch).
__device__ float g_h[337 * 512];      // h_1..h_336 (head reads t>=81)
__device__ float g_blw[256 * 512];    // sampled BayesianLinear weight
__device__ float g_blb[256];          // sampled BayesianLinear bias
__device__ u64   g_hh[2][512];        // parity buffers: (tag<<32)|h_bits

__device__ __forceinline__ float softplus_f(float x) {
  return (x > 20.f) ? x : log1pf(__expf(x));
}
__device__ __forceinline__ float sigmoid_f(float x) {
  return 1.f / (1.f + __expf(-x));
}
// Clamped fast tanh (exact to ~1e-7 pre-clamp; clamp stops __expf overflow).
__device__ __forceinline__ float tanh_f(float x) {
  x = fminf(fmaxf(x, -15.f), 15.f);
  float e = __expf(-2.f * x);
  return (1.f - e) / (1.f + e);
}

// ---------------- prep: BLW/BLb sampling + g_hh tag init ----------------
// blocks 0..511 : sample BLW -> g_blw
// block  512    : sample BLb -> g_blb; init g_hh (tag0 | h0=0 in both bufs;
//                 buf[1] tag0 != 1 so no false t=1 match)
__global__ __launch_bounds__(256) void prep_kernel(
    const float* __restrict__ blw_mu, const float* __restrict__ blw_rho, const float* __restrict__ eps_blw,
    const float* __restrict__ blb_mu, const float* __restrict__ blb_rho, const float* __restrict__ eps_blb)
{
  const int bid = blockIdx.x, tid = threadIdx.x;
  if (bid < 512) {
    const int e = bid * 256 + tid;    // < 131072
    g_blw[e] = blw_mu[e] + softplus_f(blw_rho[e]) * eps_blw[e];
  } else {
    g_blb[tid] = blb_mu[tid] + softplus_f(blb_rho[tid]) * eps_blb[tid];
    u64* p = &g_hh[0][0];
    #pragma unroll
    for (int q = 0; q < 4; ++q)
      __hip_atomic_store(p + q * 256 + tid, 0ULL, __ATOMIC_RELAXED,
                         __HIP_MEMORY_SCOPE_AGENT);
  }
}

// ---------------- persistent LSTM recurrence ----------------
// 32 WGs x 512 threads. WG r owns h-indices [16r,16r+16).
// Thread (seg=tid>>6, cl=tid&63): gate column col = (cl>>4)*512 + 16r + (cl&15),
// row range [64*seg, 64*seg+64). 64 sampled Whh weights in registers.
// KEY: wave seg's lanes poll exactly the 64 h-slots the wave's dot consumes
// -> no barrier between poll and dot. part[] is parity-double-buffered so a
// single skew-tolerant __syncthreads per step suffices.
// xg computed on the fly by wave 0 (x staged in LDS, Wih column in regs).
__global__ __launch_bounds__(512) void lstm_kernel(
    const float* __restrict__ x, const float* __restrict__ drop_x,
    const float* __restrict__ wih_mu, const float* __restrict__ wih_rho, const float* __restrict__ eps_wih,
    const float* __restrict__ b_mu, const float* __restrict__ b_rho, const float* __restrict__ eps_b,
    const float* __restrict__ whh_mu, const float* __restrict__ whh_rho, const float* __restrict__ eps_whh)
{
  const int r = blockIdx.x;         // 0..31
  const int tid = threadIdx.x;      // 0..511
  const int cl = tid & 63;
  const int seg = tid >> 6;         // 0..7
  const int gate = cl >> 4, kl = cl & 15;
  const int col = gate * 512 + r * 16 + kl;
  const int row0 = seg * 64;

  __shared__ float xd[336 * 16];    // x*drop_x for batch 255 (contiguous slice)
  __shared__ float hs[512];         // per-wave segments, wave-local use only
  __shared__ float part[2][8][64];  // parity-double-buffered partials

  // Stage xd (batch 255 slice of x is contiguous: 5376 floats).
  for (int e = tid; e < 5376; e += 512) {
    const int src = 255 * 5376 + e;
    xd[e] = x[src] * drop_x[src];
  }

  // Sample my 64 Whh weights straight into registers (FULL unroll: partial
  // unroll demotes w[] to scratch -- round-5 lesson, VGPR_Count proved it).
  float w[64];
  #pragma unroll
  for (int j = 0; j < 64; ++j) {
    const int idx = (row0 + j) * 2048 + col;
    w[j] = whh_mu[idx] + softplus_f(whh_rho[idx]) * eps_whh[idx];
  }

  // Wave 0: sample my Wih column + bias for on-the-fly xg.
  float wih[16];
  float bias = 0.f;
  if (tid < 64) {
    bias = b_mu[col] + softplus_f(b_rho[col]) * eps_b[col];
    #pragma unroll
    for (int i = 0; i < 16; ++i) {
      const int idx = i * 2048 + col;
      wih[i] = wih_mu[idx] + softplus_f(wih_rho[idx]) * eps_wih[idx];
    }
  }
  __syncthreads();                  // xd staged

  float c = 0.f;                    // cell state (wave-0 lanes 0..15)

  for (int t = 0; t < T_STEPS; ++t) {
    const int p = t & 1;

    // xg for this step (independent of h; computed before the poll).
    float xgv = 0.f;
    if (tid < 64) {
      const float4* xr = (const float4*)(xd + t * 16);
      float4 x0 = xr[0], x1 = xr[1], x2 = xr[2], x3 = xr[3];
      float s0 = fmaf(x0.x, wih[0], bias);
      s0 = fmaf(x0.y, wih[1], s0); s0 = fmaf(x0.z, wih[2], s0); s0 = fmaf(x0.w, wih[3], s0);
      float s1 = x1.x * wih[4];
      s1 = fmaf(x1.y, wih[5], s1); s1 = fmaf(x1.z, wih[6], s1); s1 = fmaf(x1.w, wih[7], s1);
      float s2 = x2.x * wih[8];
      s2 = fmaf(x2.y, wih[9], s2); s2 = fmaf(x2.z, wih[10], s2); s2 = fmaf(x2.w, wih[11], s2);
      float s3 = x3.x * wih[12];
      s3 = fmaf(x3.y, wih[13], s3); s3 = fmaf(x3.z, wih[14], s3); s3 = fmaf(x3.w, wih[15], s3);
      xgv = (s0 + s1) + (s2 + s3);
    }

    // Poll my slot (tag==t carries the h value; all-relaxed agent ops).
    {
      const u64* slot = &g_hh[p][tid];
      u64 v;
      do {
        v = __hip_atomic_load(slot, __ATOMIC_RELAXED, __HIP_MEMORY_SCOPE_AGENT);
      } while ((unsigned)(v >> 32) != (unsigned)t);
      hs[tid] = __uint_as_float((unsigned)v);
    }
    // No barrier: wave seg's dot reads hs[row0..row0+64) = its own lanes' data.

    float a0 = 0.f, a1 = 0.f, a2 = 0.f, a3 = 0.f;
    const float4* hv = (const float4*)(hs + row0);   // broadcast reads
    #pragma unroll
    for (int jj = 0; jj < 16; ++jj) {
      float4 h4 = hv[jj];
      a0 = fmaf(h4.x, w[4 * jj],     a0);
      a1 = fmaf(h4.y, w[4 * jj + 1], a1);
      a2 = fmaf(h4.z, w[4 * jj + 2], a2);
      a3 = fmaf(h4.w, w[4 * jj + 3], a3);
    }
    part[p][seg][cl] = (a0 + a1) + (a2 + a3);
    __syncthreads();   // single rendezvous per step (skew-safe via parity bufs)

    // Wave 0: reduce 8 segments, shfl gate exchange, nonlinearity, publish.
    if (tid < 64) {
      float g = xgv
              + ((part[p][0][tid] + part[p][1][tid]) + (part[p][2][tid] + part[p][3][tid]))
              + ((part[p][4][tid] + part[p][5][tid]) + (part[p][6][tid] + part[p][7][tid]));
      float vi = __shfl(g, kl);
      float vf = __shfl(g, kl + 16);
      float vg = __shfl(g, kl + 32);
      float vo = __shfl(g, kl + 48);
      if (tid < 16) {
        float ig = sigmoid_f(vi);
        float fg = sigmoid_f(vf);
        float gg = tanh_f(vg);
        float og = sigmoid_f(vo);
        c = fg * c + ig * gg;
        float h = og * tanh_f(c);
        g_h[(t + 1) * 512 + r * 16 + tid] = h;       // for head
        u64 pv = (((u64)(unsigned)(t + 1)) << 32) | (u64)__float_as_uint(h);
        __hip_atomic_store(&g_hh[(t + 1) & 1][r * 16 + tid], pv,
                           __ATOMIC_RELAXED, __HIP_MEMORY_SCOPE_AGENT);
      }
    }
  }
}

// ---------------- head ----------------
// block j: last[j] = g_h[81+j]  (reshape(T,B,H)[-1] => h_{t=80+j} of batch 255)
// y[l] = relu(last*drop_h[j] . BLW[l] + BLb[l]) * drop_l[j,l]
// out[j,o] = sum_l y[l]*lin_w[o,l]
__global__ __launch_bounds__(256) void head_kernel(
    const float* __restrict__ drop_h, const float* __restrict__ drop_l,
    const float* __restrict__ lin_w, float* __restrict__ out)
{
  const int j = blockIdx.x, tid = threadIdx.x;
  __shared__ float hd[512];
  __shared__ float y[256];

  for (int k = tid; k < 512; k += 256)
    hd[k] = g_h[(81 + j) * 512 + k] * drop_h[j * 512 + k];
  __syncthreads();

  {
    const int l = tid;
    float acc = g_blb[l];
    const float* wrow = g_blw + l * 512;
    #pragma unroll 8
    for (int k = 0; k < 512; ++k) acc = fmaf(hd[k], wrow[k], acc);
    acc = fmaxf(acc, 0.f);
    y[l] = acc * drop_l[j * 256 + l];
  }
  __syncthreads();

  if (tid < 10) {
    float acc = 0.f;
    const float* lrow = lin_w + tid * 256;
    #pragma unroll 8
    for (int l = 0; l < 256; ++l) acc = fmaf(y[l], lrow[l], acc);
    out[j * 10 + tid] = acc;
  }
}

// ---------------- launch ----------------
extern "C" void kernel_launch(void* const* d_in, const int* in_sizes, int n_in,
                              void* d_out, int out_size, void* d_ws, size_t ws_size,
                              hipStream_t stream) {
  const float* x        = (const float*)d_in[0];
  const float* drop_x   = (const float*)d_in[1];
  const float* drop_h   = (const float*)d_in[2];
  const float* drop_l   = (const float*)d_in[3];
  const float* wih_mu   = (const float*)d_in[4];
  const float* wih_rho  = (const float*)d_in[5];
  const float* eps_wih  = (const float*)d_in[6];
  const float* whh_mu   = (const float*)d_in[7];
  const float* whh_rho  = (const float*)d_in[8];
  const float* eps_whh  = (const float*)d_in[9];
  const float* b_mu     = (const float*)d_in[10];
  const float* b_rho    = (const float*)d_in[11];
  const float* eps_b    = (const float*)d_in[12];
  const float* blw_mu   = (const float*)d_in[13];
  const float* blw_rho  = (const float*)d_in[14];
  const float* eps_blw  = (const float*)d_in[15];
  const float* blb_mu   = (const float*)d_in[16];
  const float* blb_rho  = (const float*)d_in[17];
  const float* eps_blb  = (const float*)d_in[18];
  const float* lin_w    = (const float*)d_in[19];

  prep_kernel<<<513, 256, 0, stream>>>(blw_mu, blw_rho, eps_blw,
                                       blb_mu, blb_rho, eps_blb);

  lstm_kernel<<<NWG, 512, 0, stream>>>(x, drop_x,
                                       wih_mu, wih_rho, eps_wih,
                                       b_mu, b_rho, eps_b,
                                       whh_mu, whh_rho, eps_whh);

  head_kernel<<<256, 256, 0, stream>>>(drop_h, drop_l, lin_w, (float*)d_out);
}